// Round 5
// baseline (261.223 us; speedup 1.0000x reference)
//
#include <hip/hip_runtime.h>
#include <hip/hip_bf16.h>
#include <stdint.h>

namespace {
constexpr int kBatch = 256;
constexpr int kNoise = 128;
constexpr int kIn    = 512;
constexpr int kOut   = 512;
constexpr int kXCols = kNoise + kIn;        // 640
constexpr int kPCols = kIn * kOut + kOut;   // 262656 (W row stride, floats)
constexpr int kWBias = kIn * kOut;          // 262144 (bias-weight col base)
constexpr int kOTileC = 128;                // o-cols per WG (512 B contiguous DRAM granule)
constexpr int kITile  = 16;                 // i's per WG
constexpr int kNChunk = 32;                 // n-rows per WG (one K=32 MFMA step)
constexpr int kWTStride = 20;               // LDS col stride in dwords (16 kp + 4 pad, b128-aligned)
constexpr int kFeatsStride = 260;
constexpr int kSlabs = 32;                  // partial slabs (by i-split)
}

typedef __bf16 bf16x8 __attribute__((ext_vector_type(8)));
typedef float  f32x4  __attribute__((ext_vector_type(4)));
typedef unsigned int u32x4 __attribute__((ext_vector_type(4)));

__device__ inline unsigned int pack_bf16x2(float lo, float hi) {
    unsigned int a = (unsigned int)__builtin_bit_cast(unsigned short, (__bf16)lo);
    unsigned int b = (unsigned int)__builtin_bit_cast(unsigned short, (__bf16)hi);
    return a | (b << 16);
}

// Barrier draining LDS ops only; vmcnt untouched so prefetch stays in flight.
__device__ inline void wg_barrier_lds() {
    __asm__ volatile("" ::: "memory");
    __builtin_amdgcn_s_waitcnt(0xC07F);   // lgkmcnt(0)
    __builtin_amdgcn_s_barrier();
    __asm__ volatile("" ::: "memory");
}

struct PInfo { const float* p; int stride; int rowlim; };

// Grid (4 obk, 32 isp, 4 nc) = 512 WGs x 512 thr.
// WG: K-chunk n0..n0+31, o-cols o0..o0+127, i's i0..i0+15, all 256 b.
// Per pass: reads 32 rows x 512 B CONTIGUOUS from W (the DRAM-granule fix).
// feats folded into A (A' = bf16(f_i * noise)) -> oacc IS the mfma accumulator.
// Partials atomically added into 32 slabs (by isp); <=8-way contention.
__global__ __launch_bounds__(512, 4)
void hyper_gemm_kernel(const float* __restrict__ x,
                       const float* __restrict__ W,
                       const float* __restrict__ bvec,
                       float* __restrict__ part)
{
    const int tid  = threadIdx.x;
    const int lane = tid & 63;
    const int wave = tid >> 6;     // 0..7; owns m-tiles 2*wave, 2*wave+1 (b rows wave*32..+31)
    const int q    = lane >> 4;
    const int l16  = lane & 15;

    const int obk = blockIdx.x;            // 0..3
    const int isp = blockIdx.y;            // 0..31
    const int nc  = blockIdx.z;            // 0..3
    const int o0  = obk * kOTileC;
    const int i0  = isp * kITile;
    const int n0  = nc  * kNChunk;

    const bool hasBv = (nc == 0);          // feats . bvec pass
    const bool hasWb = (isp == 0);         // noise . W_bias pass
    const int nPass = kITile + (hasBv ? 1 : 0) + (hasWb ? 1 : 0);

    // W staging role: rp = row-pair 0..15, w = col-group 0..31 (cols 4w..4w+3)
    const int rp = tid >> 5;
    const int w  = tid & 31;
    const int wkey = w & 3;                        // write-side swizzle key
    const int rkey = (l16 >> 2) & 3;               // read-side swizzle key ((col>>2)&3)

    __shared__ unsigned int wtile[2][kOTileC * kWTStride];   // [col][kp] bf16 pairs, kp-block XOR swizzle
    __shared__ float feats_lds[kITile * kFeatsStride];       // [i][b]

    // pass p -> type: 0 = normal (scaled-A), 1 = feats.bvec, 2 = noise.Wbias
    auto ptype = [&](int p) -> int {
        if (p < kITile) return 0;
        if (p == kITile) return hasBv ? 1 : 2;
        return 2;
    };
    auto pinfo = [&](int p) -> PInfo {
        const int t = ptype(p);
        if (t == 0) return { W + (size_t)n0 * kPCols + (size_t)(i0 + p) * kOut + o0, kPCols, 32 };
        if (t == 1) return { bvec + (size_t)i0 * kOut + o0, kOut, kITile };
        return { W + (size_t)n0 * kPCols + kWBias + o0, kPCols, 32 };
    };
    auto load_pass = [&](int p, f32x4& lo, f32x4& hi) {
        const PInfo pi = pinfo(p);
        const int r = 2 * rp;
        if (r < pi.rowlim) {
            const float* base = pi.p + (size_t)r * pi.stride + 4 * w;
            lo = *(const f32x4*)base;
            hi = *(const f32x4*)(base + pi.stride);
        } else {
            lo = f32x4{0.f, 0.f, 0.f, 0.f};
            hi = f32x4{0.f, 0.f, 0.f, 0.f};
        }
    };

    // ---- prologue: depth-2 prefetch first ----
    f32x4 pla0, pla1, plb0, plb1;
    load_pass(0, pla0, pla1);
    load_pass(1, plb0, plb1);

    // feats[b][i0+i] -> feats_lds[i][b]
    {
        const int i    = tid & 15;
        const int brow = tid >> 4;      // 0..31
        #pragma unroll
        for (int rep = 0; rep < 8; ++rep) {
            const int b = brow + rep * 32;
            feats_lds[i * kFeatsStride + b] = x[(size_t)b * kXCols + kNoise + i0 + i];
        }
    }

    // Resident noise (fp32): per m-tile, lane's A-row b = mtile*16 + l16,
    // k = n0 + q*8 + j.  A layout: A[m=lane&15][k=q*8+j].
    f32x4 nz[2][2];   // [m][half]
    #pragma unroll
    for (int m = 0; m < 2; ++m) {
        const float* xr = x + (size_t)((wave * 2 + m) * 16 + l16) * kXCols + n0 + q * 8;
        nz[m][0] = *(const f32x4*)xr;
        nz[m][1] = *(const f32x4*)(xr + 4);
    }

    // MFMA accumulator = output partial directly (feats folded into A).
    f32x4 oacc[2][8];  // [m][o-frag]; b = (wave*2+m)*16 + q*4 + r, o = o0 + fo*16 + l16
    #pragma unroll
    for (int m = 0; m < 2; ++m)
        #pragma unroll
        for (int fo = 0; fo < 8; ++fo) oacc[m][fo] = f32x4{0.f, 0.f, 0.f, 0.f};

    __syncthreads();   // feats staged

    for (int ip = 0; ip < nPass; ++ip) {
        // pack previously-prefetched rows (vmcnt wait hits only the oldest pair)
        unsigned int pk[4];
        #pragma unroll
        for (int cc = 0; cc < 4; ++cc) pk[cc] = pack_bf16x2(pla0[cc], pla1[cc]);

        unsigned int* wt = &wtile[ip & 1][0];
        // write (col = 4w+cc, kp = rp) with kp-block XOR swizzle
        #pragma unroll
        for (int cc = 0; cc < 4; ++cc)
            wt[(4 * w + cc) * kWTStride + ((((rp >> 2) ^ wkey) << 2) | (rp & 3))] = pk[cc];

        pla0 = plb0; pla1 = plb1;
        if (ip + 2 < nPass) load_pass(ip + 2, plb0, plb1);

        wg_barrier_lds();

        // Build A fragments for this pass
        const int t = ptype(ip);
        bf16x8 afr[2];
        if (t == 0) {
            #pragma unroll
            for (int m = 0; m < 2; ++m) {
                const float f = feats_lds[ip * kFeatsStride + (wave * 2 + m) * 16 + l16];
                bf16x8 a;
                #pragma unroll
                for (int j = 0; j < 4; ++j) {
                    a[j]     = (__bf16)(f * nz[m][0][j]);
                    a[j + 4] = (__bf16)(f * nz[m][1][j]);
                }
                afr[m] = a;
            }
        } else if (t == 2) {
            #pragma unroll
            for (int m = 0; m < 2; ++m) {
                bf16x8 a;
                #pragma unroll
                for (int j = 0; j < 4; ++j) {
                    a[j]     = (__bf16)nz[m][0][j];
                    a[j + 4] = (__bf16)nz[m][1][j];
                }
                afr[m] = a;
            }
        } else {  // t == 1: A[b][kk] = feats[b][i0+kk] for kk<16, else 0
            #pragma unroll
            for (int m = 0; m < 2; ++m) {
                const int b = (wave * 2 + m) * 16 + l16;
                bf16x8 a;
                #pragma unroll
                for (int j = 0; j < 8; ++j) {
                    const int kk = q * 8 + j;
                    const float v = feats_lds[(kk & 15) * kFeatsStride + b];
                    a[j] = (kk < kITile) ? (__bf16)v : (__bf16)0.f;
                }
                afr[m] = a;
            }
        }

        // 8 o-frags x 2 m-tiles, one K=32 step each; B-frag reused across m.
        #pragma unroll
        for (int fo = 0; fo < 8; ++fo) {
            const int col = fo * 16 + l16;
            u32x4 raw = *(const u32x4*)&wt[col * kWTStride + ((q ^ rkey) << 2)];
            bf16x8 bfr = __builtin_bit_cast(bf16x8, raw);
            #pragma unroll
            for (int m = 0; m < 2; ++m)
                oacc[m][fo] = __builtin_amdgcn_mfma_f32_16x16x32_bf16(
                    afr[m], bfr, oacc[m][fo], 0, 0, 0);
        }
    }

    // ---- accumulate into slab[isp] (<=8-way contention) ----
    float* pp = part + (size_t)isp * (kBatch * kOut);
    #pragma unroll
    for (int m = 0; m < 2; ++m) {
        const int bb = (wave * 2 + m) * 16 + q * 4;
        #pragma unroll
        for (int fo = 0; fo < 8; ++fo) {
            const int o = o0 + fo * 16 + l16;
            #pragma unroll
            for (int r = 0; r < 4; ++r)
                atomicAdd(&pp[(size_t)(bb + r) * kOut + o], oacc[m][fo][r]);
        }
    }
}

// out = sum over 32 slabs + bvbias
__global__ __launch_bounds__(256)
void reduce_kernel(const float* __restrict__ part,
                   const float* __restrict__ bvec,
                   float* __restrict__ out)
{
    const size_t idx4 = ((size_t)blockIdx.x * 256 + threadIdx.x) * 4;
    const int o = (int)(idx4 & (kOut - 1));
    f32x4 acc = *(const f32x4*)(bvec + kWBias + o);
    #pragma unroll
    for (int s = 0; s < kSlabs; ++s)
        acc += *(const f32x4*)(part + (size_t)s * kBatch * kOut + idx4);
    *(f32x4*)(out + idx4) = acc;
}

extern "C" void kernel_launch(void* const* d_in, const int* in_sizes, int n_in,
                              void* d_out, int out_size, void* d_ws, size_t ws_size,
                              hipStream_t stream) {
    const float* x  = (const float*)d_in[0];
    const float* W  = (const float*)d_in[1];
    const float* bv = (const float*)d_in[2];
    float* out  = (float*)d_out;
    float* part = (float*)d_ws;   // 32 slabs * 512 KB = 16.8 MB

    hipMemsetAsync(part, 0, (size_t)kSlabs * kBatch * kOut * sizeof(float), stream);

    dim3 grid(kOut / kOTileC, kIn / kITile, kNoise / kNChunk);  // (4, 32, 4) = 512 WGs
    hyper_gemm_kernel<<<grid, 512, 0, stream>>>(x, W, bv, part);

    const int n4 = kBatch * kOut / 4;   // 32768
    reduce_kernel<<<n4 / 256, 256, 0, stream>>>(part, bv, out);
}

// Round 7
// 243.716 us; speedup vs baseline: 1.0718x; 1.0718x over previous
//
#include <hip/hip_runtime.h>
#include <hip/hip_bf16.h>
#include <stdint.h>

namespace {
constexpr int kBatch = 256;
constexpr int kNoise = 128;
constexpr int kIn    = 512;
constexpr int kOut   = 512;
constexpr int kXCols = kNoise + kIn;        // 640
constexpr int kPCols = kIn * kOut + kOut;   // 262656 (W row stride, floats)
constexpr int kWBias = kIn * kOut;          // 262144
constexpr int kOTile = 32;
constexpr int kITile = 16;
constexpr int kSplits = kIn / kITile;       // 32 partial slabs
constexpr int kWStride = 68;                // LDS col stride in dwords (64 kp + 4 pad)
constexpr int kFeatsStride = 260;
constexpr int kDepth = 8;                   // prefetch ring depth (passes)
}

typedef __bf16 bf16x8 __attribute__((ext_vector_type(8)));
typedef float  f32x2  __attribute__((ext_vector_type(2)));
typedef float  f32x4  __attribute__((ext_vector_type(4)));
typedef unsigned int u32x4 __attribute__((ext_vector_type(4)));

__device__ inline unsigned int pack_bf16x2(float lo, float hi) {
    unsigned int a = (unsigned int)__builtin_bit_cast(unsigned short, (__bf16)lo);
    unsigned int b = (unsigned int)__builtin_bit_cast(unsigned short, (__bf16)hi);
    return a | (b << 16);
}

// Barrier draining LDS ops only (lgkmcnt(0)); vmcnt untouched so the deep
// global prefetch ring stays in flight across it.
__device__ inline void wg_barrier_lds() {
    __asm__ volatile("" ::: "memory");
    __builtin_amdgcn_s_waitcnt(0xC07F);   // lgkmcnt(0), vmcnt/expcnt = no-wait
    __builtin_amdgcn_s_barrier();
    __asm__ volatile("" ::: "memory");
}

// Stage 1: part[split][b][o] = sum_{i in split} feats[b,i]*(noise@W + bvec)[b, i*512+o]
//          (+ bias term noise@W_bias + bv_bias folded into split-0 blocks as pass 17)
// Grid (16 o-tiles, 32 i-splits) = 512 WGs x 1024 thr (16 waves; wave owns 16 b-rows).
// Depth-8 register-ring prefetch: when pass ip packs, loads for ip..ip+7 are in
// flight (16 loads x 8 B x 1024 thr = 128 KB/CU) — covers ~900-cyc HBM latency.
__global__ __launch_bounds__(1024, 4)
void hyper_gemm_kernel(const float* __restrict__ x,
                       const float* __restrict__ W,
                       const float* __restrict__ bvec,
                       float* __restrict__ part)
{
    const int tid  = threadIdx.x;
    const int lane = tid & 63;
    const int wave = tid >> 6;     // 0..15, owns batch rows [wave*16, wave*16+16)
    const int q    = lane >> 4;
    const int l16  = lane & 15;

    const int o0 = blockIdx.x * kOTile;
    const int i0 = blockIdx.y * kITile;

    // W staging role: thread covers rows {2u, 2u+1}, cols {c2, c2+1}
    const int u  = tid >> 4;            // 0..63 (kp index)
    const int c2 = (tid & 15) * 2;      // 0,2,..,30

    __shared__ unsigned int wtile[2][kOTile * kWStride];   // dbuf bf16-pair tile [col][kp]
    __shared__ float feats_lds[kITile * kFeatsStride];     // [i][b] transposed
    __shared__ float bv_lds[(kITile + 1) * kOTile];        // [pass][col]

    const bool hasWb = (blockIdx.y == 0);

    auto wrow = [&](int p) -> const float* {
        return W + (size_t)(2 * u) * kPCols + (size_t)(i0 + p) * kOut + o0 + c2;
    };

    // ---- prologue ----
    // Bias-pass loads issued FIRST: vmcnt is FIFO, so they retire earliest and
    // park in 4 VGPRs until consumed after the main loop.
    f32x2 wb0{0.f, 0.f}, wb1{0.f, 0.f};
    if (hasWb) {
        const float* wp = W + (size_t)(2 * u) * kPCols + kWBias + o0 + c2;
        wb0 = *(const f32x2*)wp;
        wb1 = *(const f32x2*)(wp + kPCols);
    }

    // Depth-8 ring: passes 0..7 issued before any compute.
    f32x2 ring0[kDepth], ring1[kDepth];
    #pragma unroll
    for (int p = 0; p < kDepth; ++p) {
        const float* wp = wrow(p);
        ring0[p] = *(const f32x2*)wp;
        ring1[p] = *(const f32x2*)(wp + kPCols);
    }

    // bvec -> LDS
    for (int idx = tid; idx < (kITile + 1) * kOTile; idx += 1024) {
        const int p = idx >> 5, c = idx & 31;
        const size_t cb = (p == kITile) ? (size_t)kWBias : (size_t)(i0 + p) * kOut;
        bv_lds[idx] = bvec[cb + o0 + c];
    }

    // feats[b][i0+i] -> feats_lds[i][b]
    {
        const int i    = tid & 15;
        const int brow = tid >> 4;      // 0..63
        #pragma unroll
        for (int rep = 0; rep < 4; ++rep) {
            const int b = brow + rep * 64;
            feats_lds[i * kFeatsStride + b] = x[(size_t)b * kXCols + kNoise + i0 + i];
        }
    }

    // Noise A-fragments (resident, 16 VGPRs). A[m=lane&15][k=q*8+j], k_global=32*s+k.
    bf16x8 afrag[4];
    {
        const float* xr = x + (size_t)(wave * 16 + l16) * kXCols;
        #pragma unroll
        for (int s = 0; s < 4; ++s) {
            const float* p = xr + s * 32 + q * 8;
            f32x4 u0 = *(const f32x4*)(p);
            f32x4 u1 = *(const f32x4*)(p + 4);
            bf16x8 a;
            a[0] = (__bf16)u0[0]; a[1] = (__bf16)u0[1];
            a[2] = (__bf16)u0[2]; a[3] = (__bf16)u0[3];
            a[4] = (__bf16)u1[0]; a[5] = (__bf16)u1[1];
            a[6] = (__bf16)u1[2]; a[7] = (__bf16)u1[3];
            afrag[s] = a;
        }
    }

    float oacc[2][4];   // [nt][r]; b = wave*16+q*4+r, o = o0+nt*16+l16
    #pragma unroll
    for (int nt = 0; nt < 2; ++nt)
        #pragma unroll
        for (int r = 0; r < 4; ++r) oacc[nt][r] = 0.f;

    __syncthreads();   // feats + bvec staged

    // ---- fully-unrolled 16-pass loop, ring slot = ip & 7 (compile-time) ----
    #pragma unroll
    for (int ip = 0; ip < kITile; ++ip) {
        const int slot = ip & (kDepth - 1);

        // pack pass-ip regs (compiler waits only this slot's two loads)
        unsigned int pk0 = pack_bf16x2(ring0[slot][0], ring1[slot][0]);
        unsigned int pk1 = pack_bf16x2(ring0[slot][1], ring1[slot][1]);

        unsigned int* wt = &wtile[ip & 1][0];
        wt[(c2    ) * kWStride + u] = pk0;
        wt[(c2 + 1) * kWStride + u] = pk1;

        // refill the slot 8 passes ahead
        if (ip + kDepth < kITile) {
            const float* wp = wrow(ip + kDepth);
            ring0[slot] = *(const f32x2*)wp;
            ring1[slot] = *(const f32x2*)(wp + kPCols);
        }

        wg_barrier_lds();   // tile[ip&1] visible; prior-buffer readers drained

        // GEMM: acc[b,col] = noise @ W[:, (i0+ip)*512 + o0 + col]
        f32x4 acc[2];
        acc[0] = f32x4{0.f, 0.f, 0.f, 0.f};
        acc[1] = f32x4{0.f, 0.f, 0.f, 0.f};

        #pragma unroll
        for (int s = 0; s < 4; ++s) {
            #pragma unroll
            for (int nt = 0; nt < 2; ++nt) {
                u32x4 raw = *(const u32x4*)&wt[(nt * 16 + l16) * kWStride + s * 16 + q * 4];
                bf16x8 bfrag = __builtin_bit_cast(bf16x8, raw);
                acc[nt] = __builtin_amdgcn_mfma_f32_16x16x32_bf16(
                    afrag[s], bfrag, acc[nt], 0, 0, 0);
            }
        }

        // epilogue (fp32): oacc += feats[b,i] * (acc + bvec[c])
        const float bv0 = bv_lds[ip * kOTile + l16];
        const float bv1 = bv_lds[ip * kOTile + 16 + l16];
        const f32x4 f4 = *(const f32x4*)&feats_lds[ip * kFeatsStride + wave * 16 + q * 4];
        #pragma unroll
        for (int r = 0; r < 4; ++r) {
            oacc[0][r] += f4[r] * (acc[0][r] + bv0);
            oacc[1][r] += f4[r] * (acc[1][r] + bv1);
        }
    }

    // ---- bias pass (split-0 blocks): noise @ W_bias + bv_bias, scale = 1 ----
    if (hasWb) {
        unsigned int pk0 = pack_bf16x2(wb0[0], wb1[0]);
        unsigned int pk1 = pack_bf16x2(wb0[1], wb1[1]);
        unsigned int* wt = &wtile[0][0];   // buffer 0: last read at pass 14, drained at barrier 15
        wt[(c2    ) * kWStride + u] = pk0;
        wt[(c2 + 1) * kWStride + u] = pk1;
        wg_barrier_lds();

        f32x4 acc[2];
        acc[0] = f32x4{0.f, 0.f, 0.f, 0.f};
        acc[1] = f32x4{0.f, 0.f, 0.f, 0.f};
        #pragma unroll
        for (int s = 0; s < 4; ++s) {
            #pragma unroll
            for (int nt = 0; nt < 2; ++nt) {
                u32x4 raw = *(const u32x4*)&wt[(nt * 16 + l16) * kWStride + s * 16 + q * 4];
                bf16x8 bfrag = __builtin_bit_cast(bf16x8, raw);
                acc[nt] = __builtin_amdgcn_mfma_f32_16x16x32_bf16(
                    afrag[s], bfrag, acc[nt], 0, 0, 0);
            }
        }
        const float bv0 = bv_lds[kITile * kOTile + l16];
        const float bv1 = bv_lds[kITile * kOTile + 16 + l16];
        #pragma unroll
        for (int r = 0; r < 4; ++r) {
            oacc[0][r] += acc[0][r] + bv0;
            oacc[1][r] += acc[1][r] + bv1;
        }
    }

    // ---- stream partials (plain stores, no atomics) ----
    float* pp = part + (size_t)blockIdx.y * kBatch * kOut;
    #pragma unroll
    for (int nt = 0; nt < 2; ++nt) {
        const int o = o0 + nt * 16 + l16;
        #pragma unroll
        for (int r = 0; r < 4; ++r) {
            const int b = wave * 16 + q * 4 + r;
            pp[(size_t)b * kOut + o] = oacc[nt][r];
        }
    }
}

// Stage 2: out = sum over 32 slabs (16.8 MB, L2/L3-resident)
__global__ __launch_bounds__(256)
void reduce_kernel(const float* __restrict__ part, float* __restrict__ out)
{
    const size_t idx4 = ((size_t)blockIdx.x * 256 + threadIdx.x) * 4;
    f32x4 acc = *(const f32x4*)(part + idx4);
    #pragma unroll
    for (int s = 1; s < kSplits; ++s)
        acc += *(const f32x4*)(part + (size_t)s * kBatch * kOut + idx4);
    *(f32x4*)(out + idx4) = acc;
}

extern "C" void kernel_launch(void* const* d_in, const int* in_sizes, int n_in,
                              void* d_out, int out_size, void* d_ws, size_t ws_size,
                              hipStream_t stream) {
    const float* x  = (const float*)d_in[0];
    const float* W  = (const float*)d_in[1];
    const float* bv = (const float*)d_in[2];
    float* out  = (float*)d_out;
    float* part = (float*)d_ws;   // 32 * 256 * 512 * 4 B = 16.8 MB

    dim3 grid(kOut / kOTile, kSplits);  // (16, 32) = 512 WGs of 1024 threads
    hyper_gemm_kernel<<<grid, 1024, 0, stream>>>(x, W, bv, part);

    const int n4 = kBatch * kOut / 4;   // 32768
    reduce_kernel<<<n4 / 256, 256, 0, stream>>>(part, out);
}

// Round 9
// 241.891 us; speedup vs baseline: 1.0799x; 1.0075x over previous
//
#include <hip/hip_runtime.h>
#include <hip/hip_bf16.h>
#include <stdint.h>

namespace {
constexpr int kBatch = 256;
constexpr int kNoise = 128;
constexpr int kIn    = 512;
constexpr int kOut   = 512;
constexpr int kXCols = kNoise + kIn;        // 640
constexpr int kPCols = kIn * kOut + kOut;   // 262656 (W row stride, floats)
constexpr int kWBias = kIn * kOut;          // 262144
constexpr int kOTile = 32;
constexpr int kITile = 16;
constexpr int kSplits = kIn / kITile;       // 32 partial slabs
constexpr int kWStride = 68;                // LDS col stride in dwords (64 kp + 4 pad)
constexpr int kFeatsStride = 260;
constexpr int kDepth = 2;                   // prefetch ring depth (passes)
}

typedef __bf16 bf16x8 __attribute__((ext_vector_type(8)));
typedef float  f32x4  __attribute__((ext_vector_type(4)));
typedef unsigned int u32x4 __attribute__((ext_vector_type(4)));

__device__ inline unsigned int pack_bf16x2(float lo, float hi) {
    unsigned int a = (unsigned int)__builtin_bit_cast(unsigned short, (__bf16)lo);
    unsigned int b = (unsigned int)__builtin_bit_cast(unsigned short, (__bf16)hi);
    return a | (b << 16);
}

// Barrier draining LDS ops only (lgkmcnt(0)); vmcnt untouched so the global
// prefetch ring stays in flight across it.
__device__ inline void wg_barrier_lds() {
    __asm__ volatile("" ::: "memory");
    __builtin_amdgcn_s_waitcnt(0xC07F);   // lgkmcnt(0), vmcnt/expcnt = no-wait
    __builtin_amdgcn_s_barrier();
    __asm__ volatile("" ::: "memory");
}

// Stage 1: part[split][b][o] = sum_{i in split} feats[b,i]*(noise@W + bvec)[b, i*512+o]
//          (+ bias term noise@W_bias + bv_bias folded into split-0 blocks as pass 17)
// Grid (16 o-tiles, 32 i-splits) = 512 WGs x 512 thr.
// 8 waves/WG, wave owns 32 b-rows -> per wave-pass: 8 LDS b128 reads feed 16 MFMA
// (2x the MFMA/LDS ratio of the 16-wave variant; device LDS reads halve).
// Staging (R8 bugfix: FULL 128 rows): thread (col=tid&31, kpp=tid>>5) loads rows
// 8kpp..8kpp+7 of its col, packs 4 bf16-pair dwords, ONE b128 write at
// col*68+4*kpp (16B-aligned; 4 dwords/bank across the wave = structural minimum).
__global__ __launch_bounds__(512, 2)
void hyper_gemm_kernel(const float* __restrict__ x,
                       const float* __restrict__ W,
                       const float* __restrict__ bvec,
                       float* __restrict__ part)
{
    const int tid  = threadIdx.x;
    const int lane = tid & 63;
    const int wave = tid >> 6;     // 0..7, owns batch rows [wave*32, wave*32+32)
    const int q    = lane >> 4;
    const int l16  = lane & 15;

    const int o0 = blockIdx.x * kOTile;
    const int i0 = blockIdx.y * kITile;

    // staging role
    const int col = tid & 31;      // o-col within tile
    const int kpp = tid >> 5;      // 0..15 -> rows 8*kpp .. 8*kpp+7

    __shared__ unsigned int wtile[2][kOTile * kWStride];   // dbuf bf16-pair tile [col][kp]
    __shared__ float feats_lds[kITile * kFeatsStride];     // [i][b] transposed
    __shared__ float bv_lds[(kITile + 1) * kOTile];        // [pass][col]

    const bool hasWb = (blockIdx.y == 0);

    auto wbase = [&](int p) -> const float* {
        return W + (size_t)(8 * kpp) * kPCols + (size_t)(i0 + p) * kOut + o0 + col;
    };

    // ---- prologue ----
    // Bias-pass loads issued FIRST (FIFO-retired earliest, parked in 8 VGPRs).
    float wb[8];
    #pragma unroll
    for (int e = 0; e < 8; ++e) wb[e] = 0.f;
    if (hasWb) {
        const float* bp = W + (size_t)(8 * kpp) * kPCols + kWBias + o0 + col;
        #pragma unroll
        for (int e = 0; e < 8; ++e) wb[e] = bp[(size_t)e * kPCols];
    }

    // Depth-2 ring: 8 scalar row-loads per pass (lanes consecutive in col ->
    // 128 B coalesced per row), passes 0..1 issued up front.
    float ring[kDepth][8];
    #pragma unroll
    for (int p = 0; p < kDepth; ++p) {
        const float* wp = wbase(p);
        #pragma unroll
        for (int e = 0; e < 8; ++e)
            ring[p][e] = wp[(size_t)e * kPCols];
    }

    // bvec -> LDS  (17*32 = 544 entries)
    for (int idx = tid; idx < (kITile + 1) * kOTile; idx += 512) {
        const int p = idx >> 5, c = idx & 31;
        const size_t cb = (p == kITile) ? (size_t)kWBias : (size_t)(i0 + p) * kOut;
        bv_lds[idx] = bvec[cb + o0 + c];
    }

    // feats[b][i0+i] -> feats_lds[i][b]
    {
        const int i    = tid & 15;
        const int brow = tid >> 4;      // 0..31
        #pragma unroll
        for (int rep = 0; rep < 8; ++rep) {
            const int b = brow + rep * 32;
            feats_lds[i * kFeatsStride + b] = x[(size_t)b * kXCols + kNoise + i0 + i];
        }
    }

    // Noise A-fragments (resident, 32 VGPRs): wave rows base wave*32, 2 m-tiles.
    // A layout: A[m=lane&15][k=q*8+j], k_global = 32*s + k.
    bf16x8 afrag[2][4];
    #pragma unroll
    for (int mt = 0; mt < 2; ++mt) {
        const float* xr = x + (size_t)(wave * 32 + mt * 16 + l16) * kXCols;
        #pragma unroll
        for (int s = 0; s < 4; ++s) {
            const float* p = xr + s * 32 + q * 8;
            f32x4 u0 = *(const f32x4*)(p);
            f32x4 u1 = *(const f32x4*)(p + 4);
            bf16x8 a;
            a[0] = (__bf16)u0[0]; a[1] = (__bf16)u0[1];
            a[2] = (__bf16)u0[2]; a[3] = (__bf16)u0[3];
            a[4] = (__bf16)u1[0]; a[5] = (__bf16)u1[1];
            a[6] = (__bf16)u1[2]; a[7] = (__bf16)u1[3];
            afrag[mt][s] = a;
        }
    }

    float oacc[2][2][4];   // [mt][nt][r]; b = wave*32+mt*16+q*4+r, o = o0+nt*16+l16
    #pragma unroll
    for (int mt = 0; mt < 2; ++mt)
        #pragma unroll
        for (int nt = 0; nt < 2; ++nt)
            #pragma unroll
            for (int r = 0; r < 4; ++r) oacc[mt][nt][r] = 0.f;

    __syncthreads();   // feats + bvec staged

    // ---- fully-unrolled 16-pass loop, ring slot = ip & 1 (compile-time) ----
    #pragma unroll
    for (int ip = 0; ip < kITile; ++ip) {
        const int slot = ip & (kDepth - 1);

        // pack pass-ip rows (vmcnt wait covers only this slot's 8 loads)
        // position 4*kpp+j holds kp=4*kpp+j = rows (8kpp+2j, 8kpp+2j+1)
        u32x4 pk;
        pk[0] = pack_bf16x2(ring[slot][0], ring[slot][1]);
        pk[1] = pack_bf16x2(ring[slot][2], ring[slot][3]);
        pk[2] = pack_bf16x2(ring[slot][4], ring[slot][5]);
        pk[3] = pack_bf16x2(ring[slot][6], ring[slot][7]);

        unsigned int* wt = &wtile[ip & 1][0];
        *(u32x4*)&wt[col * kWStride + 4 * kpp] = pk;   // b128, even bank spread

        // refill the slot 2 passes ahead (rides through the lgkm-only barrier)
        if (ip + kDepth < kITile) {
            const float* wp = wbase(ip + kDepth);
            #pragma unroll
            for (int e = 0; e < 8; ++e)
                ring[slot][e] = wp[(size_t)e * kPCols];
        }

        wg_barrier_lds();   // tile[ip&1] visible; prior-buffer readers drained

        // GEMM: acc[b,col] = noise @ W[:, (i0+ip)*512 + o0 + col]
        f32x4 acc[2][2];
        #pragma unroll
        for (int mt = 0; mt < 2; ++mt)
            #pragma unroll
            for (int nt = 0; nt < 2; ++nt) acc[mt][nt] = f32x4{0.f, 0.f, 0.f, 0.f};

        #pragma unroll
        for (int s = 0; s < 4; ++s) {
            bf16x8 bfr[2];
            #pragma unroll
            for (int nt = 0; nt < 2; ++nt) {
                u32x4 raw = *(const u32x4*)&wt[(nt * 16 + l16) * kWStride + s * 16 + q * 4];
                bfr[nt] = __builtin_bit_cast(bf16x8, raw);
            }
            #pragma unroll
            for (int mt = 0; mt < 2; ++mt)
                #pragma unroll
                for (int nt = 0; nt < 2; ++nt)
                    acc[mt][nt] = __builtin_amdgcn_mfma_f32_16x16x32_bf16(
                        afrag[mt][s], bfr[nt], acc[mt][nt], 0, 0, 0);
        }

        // epilogue (fp32): oacc += feats[b,i] * (acc + bvec[c])
        const float bv0 = bv_lds[ip * kOTile + l16];
        const float bv1 = bv_lds[ip * kOTile + 16 + l16];
        #pragma unroll
        for (int mt = 0; mt < 2; ++mt) {
            // C/D layout: col = lane&15, row = q*4 + reg
            const f32x4 f4 = *(const f32x4*)&feats_lds[ip * kFeatsStride
                                    + wave * 32 + mt * 16 + q * 4];
            #pragma unroll
            for (int r = 0; r < 4; ++r) {
                oacc[mt][0][r] += f4[r] * (acc[mt][0][r] + bv0);
                oacc[mt][1][r] += f4[r] * (acc[mt][1][r] + bv1);
            }
        }
    }

    // ---- bias pass (split-0 blocks): noise @ W_bias + bv_bias, scale = 1 ----
    if (hasWb) {
        u32x4 pk;
        pk[0] = pack_bf16x2(wb[0], wb[1]);
        pk[1] = pack_bf16x2(wb[2], wb[3]);
        pk[2] = pack_bf16x2(wb[4], wb[5]);
        pk[3] = pack_bf16x2(wb[6], wb[7]);
        unsigned int* wt = &wtile[0][0];   // buf0: all reads drained at pass-15 barrier
        *(u32x4*)&wt[col * kWStride + 4 * kpp] = pk;
        wg_barrier_lds();

        f32x4 acc[2][2];
        #pragma unroll
        for (int mt = 0; mt < 2; ++mt)
            #pragma unroll
            for (int nt = 0; nt < 2; ++nt) acc[mt][nt] = f32x4{0.f, 0.f, 0.f, 0.f};

        #pragma unroll
        for (int s = 0; s < 4; ++s) {
            bf16x8 bfr[2];
            #pragma unroll
            for (int nt = 0; nt < 2; ++nt) {
                u32x4 raw = *(const u32x4*)&wt[(nt * 16 + l16) * kWStride + s * 16 + q * 4];
                bfr[nt] = __builtin_bit_cast(bf16x8, raw);
            }
            #pragma unroll
            for (int mt = 0; mt < 2; ++mt)
                #pragma unroll
                for (int nt = 0; nt < 2; ++nt)
                    acc[mt][nt] = __builtin_amdgcn_mfma_f32_16x16x32_bf16(
                        afrag[mt][s], bfr[nt], acc[mt][nt], 0, 0, 0);
        }
        const float bv0 = bv_lds[kITile * kOTile + l16];
        const float bv1 = bv_lds[kITile * kOTile + 16 + l16];
        #pragma unroll
        for (int mt = 0; mt < 2; ++mt)
            #pragma unroll
            for (int r = 0; r < 4; ++r) {
                oacc[mt][0][r] += acc[mt][0][r] + bv0;
                oacc[mt][1][r] += acc[mt][1][r] + bv1;
            }
    }

    // ---- stream partials (plain stores, no atomics) ----
    float* pp = part + (size_t)blockIdx.y * kBatch * kOut;
    #pragma unroll
    for (int mt = 0; mt < 2; ++mt)
        #pragma unroll
        for (int nt = 0; nt < 2; ++nt) {
            const int o = o0 + nt * 16 + l16;
            #pragma unroll
            for (int r = 0; r < 4; ++r) {
                const int b = wave * 32 + mt * 16 + q * 4 + r;
                pp[(size_t)b * kOut + o] = oacc[mt][nt][r];
            }
        }
}

// Stage 2: out = sum over 32 slabs (16.8 MB, L2/L3-resident)
__global__ __launch_bounds__(256)
void reduce_kernel(const float* __restrict__ part, float* __restrict__ out)
{
    const size_t idx4 = ((size_t)blockIdx.x * 256 + threadIdx.x) * 4;
    f32x4 acc = *(const f32x4*)(part + idx4);
    #pragma unroll
    for (int s = 1; s < kSplits; ++s)
        acc += *(const f32x4*)(part + (size_t)s * kBatch * kOut + idx4);
    *(f32x4*)(out + idx4) = acc;
}

extern "C" void kernel_launch(void* const* d_in, const int* in_sizes, int n_in,
                              void* d_out, int out_size, void* d_ws, size_t ws_size,
                              hipStream_t stream) {
    const float* x  = (const float*)d_in[0];
    const float* W  = (const float*)d_in[1];
    const float* bv = (const float*)d_in[2];
    float* out  = (float*)d_out;
    float* part = (float*)d_ws;   // 32 * 256 * 512 * 4 B = 16.8 MB

    dim3 grid(kOut / kOTile, kSplits);  // (16, 32) = 512 WGs of 512 threads
    hyper_gemm_kernel<<<grid, 512, 0, stream>>>(x, W, bv, part);

    const int n4 = kBatch * kOut / 4;   // 32768
    reduce_kernel<<<n4 / 256, 256, 0, stream>>>(part, out);
}